// Round 16
// baseline (514.713 us; speedup 1.0000x reference)
//
#include <hip/hip_runtime.h>
#include <hip/hip_bf16.h>

// Problem constants
#define NB 4
#define NC 256
#define ND 32
#define WH 1024          // W*H
#define DWH 32768        // D*W*H
#define KTOT 1024        // 4 modalities * 256 channels

typedef __attribute__((ext_vector_type(8))) short short8;
typedef __attribute__((ext_vector_type(4))) float f32x4;

static __device__ __forceinline__ unsigned short f32_to_bf16(float f) {
    unsigned u = __builtin_bit_cast(unsigned, f);
    u = u + 0x7fff + ((u >> 16) & 1);   // round-to-nearest-even
    return (unsigned short)(u >> 16);
}

// HW-packed convert: v_cvt_pk_bf16_f32 (1 instr per pair).
static __device__ __forceinline__ unsigned pack_bf16x2(float lo, float hi) {
    __hip_bfloat162 h = __float22bfloat162_rn(make_float2(lo, hi));
    unsigned u;
    __builtin_memcpy(&u, &h, 4);
    return u;
}

// ===========================================================================
// K1 (R16): fused pool + bf16 transcode, CONTIGUOUS-READ single-barrier form.
// Block = (b, m, cb8 = 8-channel group, d): 16384 blocks. Each block reads
// 8 channels x 4KB FULLY CONTIGUOUS per channel (vs R15's 512B-strided
// pieces -- the 44%-HBM-efficiency culprit), stages to LDS [8][1024] f32,
// one barrier, transpose-reads (b128, conflict-free), packs bf16, stores.
// Store scatter (16B per 512B) proven perf-null (R13 vs R14). Bt layout
// IDENTICAL to R13-R15: tiles [b][xt(256)][kt(16)] of [xl(128)][k(64)].
// ===========================================================================
__global__ __launch_bounds__(256) void transpool_kernel(
    const float* __restrict__ i0, const float* __restrict__ i1,
    const float* __restrict__ i2, const float* __restrict__ i3,
    unsigned short* __restrict__ Bt, float* __restrict__ pooled)
{
    __shared__ float lds[8 * 1024];   // [ci][x], 32 KB
    // XCD-chunked swizzle (16384 % 8 == 0, bijective): each XCD gets a
    // d-contiguous run -> near-sequential HBM streams per channel.
    int raw = blockIdx.x;
    int sb  = (raw & 7) * 2048 + (raw >> 3);
    int d    = sb & 31;
    int cb8  = (sb >> 5) & 31;       // 8-channel group (0..31)
    int m    = (sb >> 10) & 3;
    int b    = sb >> 12;
    const float* base = (m == 0 ? i0 : m == 1 ? i1 : m == 2 ? i2 : i3)
                        + ((size_t)(b * NC + cb8 * 8)) * DWH + d * WH;

    int t = threadIdx.x;
    int row    = t >> 5;             // channel-local ci (0..7)
    int lane32 = t & 31;

    // ---- read 8 x 4KB contiguous; all 8 loads in flight at once ----
    float4 v[8];
    #pragma unroll
    for (int j = 0; j < 8; ++j)
        v[j] = *(const float4*)(base + (size_t)row * DWH + lane32 * 4 + j * 128);

    // ---- pool partial: thread sums its 32 floats of channel (cb8*8+row) ----
    float s = 0.f;
    #pragma unroll
    for (int j = 0; j < 8; ++j)
        s += (v[j].x + v[j].y) + (v[j].z + v[j].w);

    // ---- stage to LDS (b128, conflict-free) ----
    #pragma unroll
    for (int j = 0; j < 8; ++j)
        *(float4*)&lds[row * 1024 + lane32 * 4 + j * 128] = v[j];
    __syncthreads();

    // ---- transpose-read + pack + store ----
    // Thread t owns x = 4t .. 4t+3. Read lds[ci][4t..4t+4) as float4 (b128:
    // lanes 16B apart, conflict-free); pack k-contiguous 16B = 8 channels.
    float4 c0 = *(const float4*)&lds[0 * 1024 + 4 * t];
    float4 c1 = *(const float4*)&lds[1 * 1024 + 4 * t];
    float4 c2 = *(const float4*)&lds[2 * 1024 + 4 * t];
    float4 c3 = *(const float4*)&lds[3 * 1024 + 4 * t];
    float4 c4 = *(const float4*)&lds[4 * 1024 + 4 * t];
    float4 c5 = *(const float4*)&lds[5 * 1024 + 4 * t];
    float4 c6 = *(const float4*)&lds[6 * 1024 + 4 * t];
    float4 c7 = *(const float4*)&lds[7 * 1024 + 4 * t];

    // tile base: (b, xt = d*8 + s, kt = m*4 + cb8>>3), k-offset (cb8&7)*8
    unsigned short* tb0 = Bt + (((size_t)b * 256 + d * 8) * 16
                                + (m * 4 + (cb8 >> 3))) * 8192
                             + (cb8 & 7) * 8;
    #pragma unroll
    for (int xi = 0; xi < 4; ++xi) {
        int x = 4 * t + xi;
        const float* f0 = (const float*)&c0;  const float* f1 = (const float*)&c1;
        const float* f2 = (const float*)&c2;  const float* f3 = (const float*)&c3;
        const float* f4 = (const float*)&c4;  const float* f5 = (const float*)&c5;
        const float* f6 = (const float*)&c6;  const float* f7 = (const float*)&c7;
        uint4 pk = (uint4){pack_bf16x2(f0[xi], f1[xi]),
                           pack_bf16x2(f2[xi], f3[xi]),
                           pack_bf16x2(f4[xi], f5[xi]),
                           pack_bf16x2(f6[xi], f7[xi])};
        *(uint4*)(tb0 + (size_t)(x >> 7) * 16 * 8192 + (size_t)(x & 127) * 64) = pk;
    }

    // ---- pool reduce over the 32 lanes of this channel-row ----
    s += __shfl_down(s, 16, 64);
    s += __shfl_down(s, 8, 64);
    s += __shfl_down(s, 4, 64);
    s += __shfl_down(s, 2, 64);
    s += __shfl_down(s, 1, 64);
    if (lane32 == 0) {
        int c = cb8 * 8 + row;
        pooled[((size_t)b * NC + c) * 128 + m * 32 + d] = s * (1.0f / 1024.0f);
    }
}

// ===========================================================================
// FALLBACK K1: pool only (used when ws too small).
// ===========================================================================
__global__ __launch_bounds__(256) void pool_kernel(
    const float* __restrict__ i0, const float* __restrict__ i1,
    const float* __restrict__ i2, const float* __restrict__ i3,
    float* __restrict__ pooled)
{
    int bid = blockIdx.x;
    int m   = bid & 3;
    int bc  = bid >> 2;
    const float* src = (m == 0 ? i0 : m == 1 ? i1 : m == 2 ? i2 : i3)
                       + (size_t)bc * DWH;
    int t = threadIdx.x;
    int d   = t >> 3;
    int sub = t & 7;

    const float4* row = (const float4*)(src + (size_t)d * WH);
    float4 a0 = {0.f, 0.f, 0.f, 0.f}, a1 = {0.f, 0.f, 0.f, 0.f};
    #pragma unroll
    for (int j = 0; j < 16; ++j) {
        float4 u = row[sub + 8 * (2 * j)];
        float4 w = row[sub + 8 * (2 * j + 1)];
        a0.x += u.x; a0.y += u.y; a0.z += u.z; a0.w += u.w;
        a1.x += w.x; a1.y += w.y; a1.z += w.z; a1.w += w.w;
    }
    float s = (a0.x + a0.y) + (a0.z + a0.w) + (a1.x + a1.y) + (a1.z + a1.w);
    s += __shfl_down(s, 4, 64);
    s += __shfl_down(s, 2, 64);
    s += __shfl_down(s, 1, 64);
    if (sub == 0) pooled[bc * 128 + m * 32 + d] = s * (1.0f / 1024.0f);
}

// ---------------------------------------------------------------------------
// Kernel 2: attention weights + effective GEMM A-matrix + effective bias.
// ---------------------------------------------------------------------------
__global__ __launch_bounds__(64) void attn_kernel(
    const float* __restrict__ pooled,
    const float* __restrict__ Wq, const float* __restrict__ bq,
    const float* __restrict__ Wk, const float* __restrict__ bk,
    const float* __restrict__ Wc, const float* __restrict__ bcv,
    unsigned short* __restrict__ Amat, float* __restrict__ beff)
{
    int bc_idx = blockIdx.x;             // b*NC + c
    int lane = threadIdx.x;
    int e = lane & 31;
    const float* P = pooled + bc_idx * 128;

    float q = 0.f, kv[4] = {0.f, 0.f, 0.f, 0.f};
    for (int d = 0; d < 32; ++d) {
        float pq = P[d];
        float wq = Wq[e * 32 + d], wk = Wk[e * 32 + d];
        q += pq * wq;
        #pragma unroll
        for (int m = 0; m < 4; ++m) kv[m] += P[m * 32 + d] * wk;
    }
    q += bq[e];
    #pragma unroll
    for (int m = 0; m < 4; ++m) kv[m] += bk[e];

    float lg[4];
    #pragma unroll
    for (int m = 0; m < 4; ++m) {
        float p = q * kv[m];
        #pragma unroll
        for (int off = 16; off; off >>= 1) p += __shfl_xor(p, off, 32);
        lg[m] = p * 0.17677669529663687f;    // 1/sqrt(32)
    }
    float mx = fmaxf(fmaxf(lg[0], lg[1]), fmaxf(lg[2], lg[3]));
    float ex[4], s = 0.f;
    #pragma unroll
    for (int m = 0; m < 4; ++m) { ex[m] = __expf(lg[m] - mx); s += ex[m]; }
    float a[4];
    #pragma unroll
    for (int m = 0; m < 4; ++m) a[m] = ex[m] / s;

    int c = bc_idx & 255;
    if (lane == 0) {
        float be = 0.f;
        #pragma unroll
        for (int m = 0; m < 4; ++m) be += a[m] * bcv[m * NC + c];
        beff[bc_idx] = be;
    }
    unsigned short* Arow = Amat + (size_t)bc_idx * KTOT;
    #pragma unroll
    for (int j = 0; j < 16; ++j) {
        int k = j * 64 + lane;
        int m = k >> 8, cin = k & 255;
        float v = a[m] * Wc[(m * NC + c) * NC + cin];
        Arow[k] = f32_to_bf16(v);
    }
}

#define BM 128
#define BN 128
#define BK 64

static __device__ __forceinline__ int swzA(int row, int chunk) {
    // ushort units: row stride 64 ushorts (=128B), chunk = 8 ushorts (=16B)
    return row * 64 + ((chunk ^ (row & 7)) << 3);
}
static __device__ __forceinline__ int swzB(int row, int chunk) {
    return row * 64 + ((chunk ^ ((row >> 1) & 7)) << 3);
}

// ===========================================================================
// K3: all-bf16 GEMM (verified R13-R15, ~100 us). A and B both staged via
// global_load_lds (pre-swizzled source, linear LDS dest), double-buffered
// one K-tile ahead; the only in-loop wait is counted vmcnt(8).
// ===========================================================================
__global__ __launch_bounds__(256, 2) void gemm2_kernel(
    const unsigned short* __restrict__ Amat,
    const unsigned short* __restrict__ Bt,
    const float* __restrict__ beff,
    float* __restrict__ out)
{
    __shared__ __align__(16) short As[2 * BM * BK];   // 32KB dbuf
    __shared__ __align__(16) short Bs[2 * BN * BK];   // 32KB dbuf

    int raw = blockIdx.x;
    int sb  = (raw & 7) * 256 + (raw >> 3);
    int ot = sb & 1;
    int xt = (sb >> 1) & 255;
    int b  = sb >> 9;
    int o0 = ot * BM, x0 = xt * BN;

    int t = threadIdx.x;
    int wave = t >> 6, lane = t & 63;
    int wr = wave >> 1, wc = wave & 1;
    int lrow = lane & 15, lk = lane >> 4;
    int lr8 = lane >> 3;
    int aq  = (lane & 7) ^ lr8;

    const unsigned short* asrc = Amat + ((size_t)b * NC + o0) * KTOT
                                 + (size_t)(wave * 32 + lr8) * KTOT + aq * 8;
    const unsigned short* bsrc = Bt + ((size_t)b * 256 + xt) * 16 * 8192
                                 + (size_t)(wave * 32 + lr8) * 64 + aq * 8;

    f32x4 acc[4][4];
    #pragma unroll
    for (int mi = 0; mi < 4; ++mi)
        #pragma unroll
        for (int ni = 0; ni < 4; ++ni)
            acc[mi][ni] = (f32x4){0.f, 0.f, 0.f, 0.f};

    // ---- prologue: issue tile 0 into buf0 (8 vmem per wave) ----
    #pragma unroll
    for (int p = 0; p < 4; ++p)
        __builtin_amdgcn_global_load_lds(
            (const __attribute__((address_space(1))) unsigned int*)
                (asrc + (size_t)p * 8 * KTOT),
            (__attribute__((address_space(3))) unsigned int*)
                (As + (wave * 32 + p * 8) * 64), 16, 0, 0);
    #pragma unroll
    for (int p = 0; p < 4; ++p)
        __builtin_amdgcn_global_load_lds(
            (const __attribute__((address_space(1))) unsigned int*)
                (bsrc + (size_t)p * 8 * 64),
            (__attribute__((address_space(3))) unsigned int*)
                (Bs + (wave * 32 + p * 8) * 64), 16, 0, 0);
    __builtin_amdgcn_sched_barrier(0);

    #pragma unroll 1
    for (int it = 0; it < 16; ++it) {
        // ---- issue next tile -> buf^1 (8 vmem; last iter re-issues 15) ----
        int ja = (it < 15) ? it + 1 : 15;
        int bo = ((it + 1) & 1) * (BM * BK);
        #pragma unroll
        for (int p = 0; p < 4; ++p)
            __builtin_amdgcn_global_load_lds(
                (const __attribute__((address_space(1))) unsigned int*)
                    (asrc + (size_t)p * 8 * KTOT + ja * BK),
                (__attribute__((address_space(3))) unsigned int*)
                    (As + bo + (wave * 32 + p * 8) * 64), 16, 0, 0);
        #pragma unroll
        for (int p = 0; p < 4; ++p)
            __builtin_amdgcn_global_load_lds(
                (const __attribute__((address_space(1))) unsigned int*)
                    (bsrc + (size_t)ja * 8192 + p * 8 * 64),
                (__attribute__((address_space(3))) unsigned int*)
                    (Bs + bo + (wave * 32 + p * 8) * 64), 16, 0, 0);
        __builtin_amdgcn_sched_barrier(0);

        // ---- current tile's 8 loads landed (8 newer in flight) ----
        asm volatile("s_waitcnt vmcnt(8)" ::: "memory");
        __builtin_amdgcn_s_barrier();
        __builtin_amdgcn_sched_barrier(0);

        // ---- compute on buf cur ----
        const short* Acur = As + (it & 1) * (BM * BK);
        const short* Bcur = Bs + (it & 1) * (BM * BK);
        #pragma unroll
        for (int kk = 0; kk < 2; ++kk) {
            int q = kk * 4 + lk;
            short8 af[4], bf[4];
            #pragma unroll
            for (int mi = 0; mi < 4; ++mi)
                af[mi] = *(const short8*)(&Acur[swzA(wr * 64 + mi * 16 + lrow, q)]);
            #pragma unroll
            for (int ni = 0; ni < 4; ++ni)
                bf[ni] = *(const short8*)(&Bcur[swzA(wc * 64 + ni * 16 + lrow, q)]);
            __builtin_amdgcn_s_setprio(1);
            #pragma unroll
            for (int mi = 0; mi < 4; ++mi)
                #pragma unroll
                for (int ni = 0; ni < 4; ++ni)
                    acc[mi][ni] = __builtin_amdgcn_mfma_f32_16x16x32_bf16(
                        af[mi], bf[ni], acc[mi][ni], 0, 0, 0);
            __builtin_amdgcn_s_setprio(0);
        }
        // ---- all waves done reading buf cur (next iter overwrites it) ----
        __builtin_amdgcn_s_barrier();
        __builtin_amdgcn_sched_barrier(0);
    }

    // ---- epilogue ----
    const float* beff_b = beff + b * NC + o0;
    float* outb = out + ((size_t)b * NC + o0) * DWH + x0;
    #pragma unroll
    for (int mi = 0; mi < 4; ++mi) {
        #pragma unroll
        for (int r4 = 0; r4 < 4; ++r4) {
            int row = wr * 64 + mi * 16 + lk * 4 + r4;
            float bias = beff_b[row];
            float* orow = outb + (size_t)row * DWH;
            #pragma unroll
            for (int ni = 0; ni < 4; ++ni) {
                int col = wc * 64 + ni * 16 + lrow;
                orow[col] = acc[mi][ni][r4] + bias;
            }
        }
    }
}

// ===========================================================================
// FALLBACK K3: R12 gemm (fp32 B reg-staged + cvt_pk).
// ===========================================================================
__global__ __launch_bounds__(256, 3) void gemm_kernel(
    const float* __restrict__ i0, const float* __restrict__ i1,
    const float* __restrict__ i2, const float* __restrict__ i3,
    const unsigned short* __restrict__ Amat,
    const float* __restrict__ beff,
    float* __restrict__ out)
{
    __shared__ __align__(16) short As[2 * BM * BK];
    __shared__ __align__(16) short Bs[BN * BK];

    int raw = blockIdx.x;
    int sb  = (raw & 7) * 256 + (raw >> 3);
    int ot = sb & 1;
    int xt = (sb >> 1) & 255;
    int b  = sb >> 9;
    int o0 = ot * BM, x0 = xt * BN;

    const unsigned short* Ab = Amat + ((size_t)b * NC + o0) * KTOT;

    int t = threadIdx.x;
    int wave = t >> 6, lane = t & 63;
    int wr = wave >> 1, wc = wave & 1;
    int lrow = lane & 15, lk = lane >> 4;

    f32x4 acc[4][4];
    #pragma unroll
    for (int mi = 0; mi < 4; ++mi)
        #pragma unroll
        for (int ni = 0; ni < 4; ++ni)
            acc[mi][ni] = (f32x4){0.f, 0.f, 0.f, 0.f};

    int xq = t & 31;
    int kb = (t >> 5) * 8;

    int ar = wave * 32 + (lane >> 3);
    int aq = (lane & 7) ^ (lane >> 3);
    const unsigned short* asrc = Ab + (size_t)ar * KTOT + aq * 8;

    float4 v[8];

    {
        #pragma unroll
        for (int p = 0; p < 4; ++p)
            __builtin_amdgcn_global_load_lds(
                (const __attribute__((address_space(1))) unsigned int*)
                    (asrc + (size_t)p * 8 * KTOT),
                (__attribute__((address_space(3))) unsigned int*)
                    (As + (wave * 32 + p * 8) * 64), 16, 0, 0);
        const float* Bb = i0 + (size_t)b * NC * DWH + x0;
        #pragma unroll
        for (int j = 0; j < 8; ++j)
            v[j] = *(const float4*)(Bb + (size_t)(kb + j) * DWH + xq * 4);
    }

    #pragma unroll 1
    for (int it = 0; it < KTOT / BK; ++it) {
        const short* Acur = As + (it & 1) * (BM * BK);
        short* Anx = As + ((it + 1) & 1) * (BM * BK);

        __builtin_amdgcn_s_barrier();
        __builtin_amdgcn_sched_barrier(0);

        {
            int ja = (it + 1 < 16) ? it + 1 : 15;
            #pragma unroll
            for (int p = 0; p < 4; ++p)
                __builtin_amdgcn_global_load_lds(
                    (const __attribute__((address_space(1))) unsigned int*)
                        (asrc + (size_t)p * 8 * KTOT + ja * BK),
                    (__attribute__((address_space(3))) unsigned int*)
                        (Anx + (wave * 32 + p * 8) * 64), 16, 0, 0);
        }
        __builtin_amdgcn_sched_barrier(0);

        uint4 pk[4];
        #pragma unroll
        for (int i = 0; i < 4; ++i) {
            unsigned w[4];
            #pragma unroll
            for (int j = 0; j < 4; ++j)
                w[j] = pack_bf16x2(((const float*)&v[2 * j])[i],
                                   ((const float*)&v[2 * j + 1])[i]);
            pk[i] = (uint4){w[0], w[1], w[2], w[3]};
        }

        {
            int itn = (it < 15) ? it + 1 : 15;
            int m = itn >> 2, cbase = (itn & 3) * 64;
            const float* Bb = (m == 0 ? i0 : m == 1 ? i1 : m == 2 ? i2 : i3)
                              + ((size_t)b * NC + cbase) * DWH + x0;
            #pragma unroll
            for (int j = 0; j < 8; ++j)
                v[j] = *(const float4*)(Bb + (size_t)(kb + j) * DWH + xq * 4);
        }
        __builtin_amdgcn_sched_barrier(0);

        #pragma unroll
        for (int i = 0; i < 4; ++i)
            *(uint4*)(&Bs[swzB(xq * 4 + i, t >> 5)]) = pk[i];

        asm volatile("s_waitcnt vmcnt(12) lgkmcnt(0)" ::: "memory");
        __builtin_amdgcn_s_barrier();
        __builtin_amdgcn_sched_barrier(0);

        #pragma unroll
        for (int kk = 0; kk < 2; ++kk) {
            int q = kk * 4 + lk;
            short8 af[4], bf[4];
            #pragma unroll
            for (int mi = 0; mi < 4; ++mi)
                af[mi] = *(const short8*)(&Acur[swzA(wr * 64 + mi * 16 + lrow, q)]);
            #pragma unroll
            for (int ni = 0; ni < 4; ++ni)
                bf[ni] = *(const short8*)(&Bs[swzB(wc * 64 + ni * 16 + lrow, q)]);
            __builtin_amdgcn_s_setprio(1);
            #pragma unroll
            for (int mi = 0; mi < 4; ++mi)
                #pragma unroll
                for (int ni = 0; ni < 4; ++ni)
                    acc[mi][ni] = __builtin_amdgcn_mfma_f32_16x16x32_bf16(
                        af[mi], bf[ni], acc[mi][ni], 0, 0, 0);
            __builtin_amdgcn_s_setprio(0);
        }
    }

    const float* beff_b = beff + b * NC + o0;
    float* outb = out + ((size_t)b * NC + o0) * DWH + x0;
    #pragma unroll
    for (int mi = 0; mi < 4; ++mi) {
        #pragma unroll
        for (int r4 = 0; r4 < 4; ++r4) {
            int row = wr * 64 + mi * 16 + lk * 4 + r4;
            float bias = beff_b[row];
            float* orow = outb + (size_t)row * DWH;
            #pragma unroll
            for (int ni = 0; ni < 4; ++ni) {
                int col = wc * 64 + ni * 16 + lrow;
                orow[col] = acc[mi][ni][r4] + bias;
            }
        }
    }
}

// ---------------------------------------------------------------------------
extern "C" void kernel_launch(void* const* d_in, const int* in_sizes, int n_in,
                              void* d_out, int out_size, void* d_ws, size_t ws_size,
                              hipStream_t stream) {
    const float* m1 = (const float*)d_in[0];
    const float* m2 = (const float*)d_in[1];
    const float* m3 = (const float*)d_in[2];
    const float* m4 = (const float*)d_in[3];
    const float* Wq = (const float*)d_in[4];
    const float* bq = (const float*)d_in[5];
    const float* Wk = (const float*)d_in[6];
    const float* bk = (const float*)d_in[7];
    const float* Wc = (const float*)d_in[8];
    const float* bcv = (const float*)d_in[9];
    float* out = (float*)d_out;

    const size_t BT_BYTES = (size_t)NB * KTOT * DWH * 2;   // 256 MB
    const size_t NEED = BT_BYTES + 524288 + 2097152 + 4096;

    if (ws_size >= NEED) {
        // transcode+pool -> attn -> all-bf16 gemm
        unsigned short* Btr   = (unsigned short*)d_ws;
        float* pooled         = (float*)((char*)d_ws + BT_BYTES);
        unsigned short* Amat  = (unsigned short*)((char*)d_ws + BT_BYTES + 524288);
        float* beff           = (float*)((char*)d_ws + BT_BYTES + 524288 + 2097152);

        transpool_kernel<<<16384, 256, 0, stream>>>(m1, m2, m3, m4, Btr, pooled);
        attn_kernel<<<NB * NC, 64, 0, stream>>>(pooled, Wq, bq, Wk, bk, Wc, bcv,
                                                Amat, beff);
        gemm2_kernel<<<2048, 256, 0, stream>>>(Amat, Btr, beff, out);
    } else {
        // FALLBACK: measured R12 path
        float* pooled        = (float*)d_ws;
        unsigned short* Amat = (unsigned short*)((char*)d_ws + 524288);
        float* beff          = (float*)((char*)d_ws + 524288 + 2097152);

        pool_kernel<<<NB * NC * 4, 256, 0, stream>>>(m1, m2, m3, m4, pooled);
        attn_kernel<<<NB * NC, 64, 0, stream>>>(pooled, Wq, bq, Wk, bk, Wc, bcv,
                                                Amat, beff);
        gemm_kernel<<<(NB) * (NC / BM) * (DWH / BN), 256, 0, stream>>>(
            m1, m2, m3, m4, Amat, beff, out);
    }
}

// Round 17
// 294.896 us; speedup vs baseline: 1.7454x; 1.7454x over previous
//
#include <hip/hip_runtime.h>
#include <hip/hip_bf16.h>

// Problem constants
#define NB 4
#define NC 256
#define ND 32
#define WH 1024          // W*H
#define DWH 32768        // D*W*H
#define KTOT 1024        // 4 modalities * 256 channels

typedef __attribute__((ext_vector_type(8))) short short8;
typedef __attribute__((ext_vector_type(4))) float f32x4;

static __device__ __forceinline__ unsigned short f32_to_bf16(float f) {
    unsigned u = __builtin_bit_cast(unsigned, f);
    u = u + 0x7fff + ((u >> 16) & 1);   // round-to-nearest-even
    return (unsigned short)(u >> 16);
}

// HW-packed convert: v_cvt_pk_bf16_f32 (1 instr per pair).
static __device__ __forceinline__ unsigned pack_bf16x2(float lo, float hi) {
    __hip_bfloat162 h = __float22bfloat162_rn(make_float2(lo, hi));
    unsigned u;
    __builtin_memcpy(&u, &h, 4);
    return u;
}

// ===========================================================================
// K1 (R17): fused pool + bf16 transcode. R16's contiguous-read single-barrier
// structure (verified correct) + NEW Bt2 layout so each block's writes are
// SELF-CONTAINED FULL LINES (R16's layout split every 128B k-row across 4
// blocks -> partial-line RMW, WRITE_SIZE 2.2x).
//   Bt2[b][kt(16)][kc(8)][X(32768)] of 16B chunks (8 ushorts):
//   block (b,m,cb8,d) writes X = d*1024..+1023 for (kt=m*4+cb8>>3, kc=cb8&7)
//   -> 16KB contiguous per block, 64B contiguous per thread.
// ===========================================================================
__global__ __launch_bounds__(256) void transpool_kernel(
    const float* __restrict__ i0, const float* __restrict__ i1,
    const float* __restrict__ i2, const float* __restrict__ i3,
    unsigned short* __restrict__ Bt, float* __restrict__ pooled)
{
    __shared__ float lds[8 * 1024];   // [ci][x], 32 KB
    // XCD-chunked bijective swizzle (16384 % 8 == 0).
    int raw = blockIdx.x;
    int sb  = (raw & 7) * 2048 + (raw >> 3);
    int d    = sb & 31;
    int cb8  = (sb >> 5) & 31;       // 8-channel group (0..31)
    int m    = (sb >> 10) & 3;
    int b    = sb >> 12;
    const float* base = (m == 0 ? i0 : m == 1 ? i1 : m == 2 ? i2 : i3)
                        + ((size_t)(b * NC + cb8 * 8)) * DWH + d * WH;

    int t = threadIdx.x;
    int row    = t >> 5;             // channel-local ci (0..7)
    int lane32 = t & 31;

    // ---- read 8 x 4KB contiguous; all 8 loads in flight at once ----
    float4 v[8];
    #pragma unroll
    for (int j = 0; j < 8; ++j)
        v[j] = *(const float4*)(base + (size_t)row * DWH + lane32 * 4 + j * 128);

    // ---- pool partial: thread sums its 32 floats of channel (cb8*8+row) ----
    float s = 0.f;
    #pragma unroll
    for (int j = 0; j < 8; ++j)
        s += (v[j].x + v[j].y) + (v[j].z + v[j].w);

    // ---- stage to LDS (b128, conflict-free) ----
    #pragma unroll
    for (int j = 0; j < 8; ++j)
        *(float4*)&lds[row * 1024 + lane32 * 4 + j * 128] = v[j];
    __syncthreads();

    // ---- transpose-read (b128, lanes 16B apart: conflict-free) + pack ----
    float4 c0 = *(const float4*)&lds[0 * 1024 + 4 * t];
    float4 c1 = *(const float4*)&lds[1 * 1024 + 4 * t];
    float4 c2 = *(const float4*)&lds[2 * 1024 + 4 * t];
    float4 c3 = *(const float4*)&lds[3 * 1024 + 4 * t];
    float4 c4 = *(const float4*)&lds[4 * 1024 + 4 * t];
    float4 c5 = *(const float4*)&lds[5 * 1024 + 4 * t];
    float4 c6 = *(const float4*)&lds[6 * 1024 + 4 * t];
    float4 c7 = *(const float4*)&lds[7 * 1024 + 4 * t];

    // ---- store: 64B contiguous per thread, 16KB contiguous per block ----
    int kt = m * 4 + (cb8 >> 3);
    int kc = cb8 & 7;
    unsigned short* dst = Bt
        + ((((size_t)b * 16 + kt) * 8 + kc) * 32768 + (size_t)d * 1024 + 4 * t) * 8;
    const float* f0 = (const float*)&c0;  const float* f1 = (const float*)&c1;
    const float* f2 = (const float*)&c2;  const float* f3 = (const float*)&c3;
    const float* f4 = (const float*)&c4;  const float* f5 = (const float*)&c5;
    const float* f6 = (const float*)&c6;  const float* f7 = (const float*)&c7;
    #pragma unroll
    for (int xi = 0; xi < 4; ++xi) {
        uint4 pk = (uint4){pack_bf16x2(f0[xi], f1[xi]),
                           pack_bf16x2(f2[xi], f3[xi]),
                           pack_bf16x2(f4[xi], f5[xi]),
                           pack_bf16x2(f6[xi], f7[xi])};
        *(uint4*)(dst + xi * 8) = pk;
    }

    // ---- pool reduce over the 32 lanes of this channel-row ----
    s += __shfl_down(s, 16, 64);
    s += __shfl_down(s, 8, 64);
    s += __shfl_down(s, 4, 64);
    s += __shfl_down(s, 2, 64);
    s += __shfl_down(s, 1, 64);
    if (lane32 == 0) {
        int c = cb8 * 8 + row;
        pooled[((size_t)b * NC + c) * 128 + m * 32 + d] = s * (1.0f / 1024.0f);
    }
}

// ===========================================================================
// FALLBACK K1: pool only (used when ws too small).
// ===========================================================================
__global__ __launch_bounds__(256) void pool_kernel(
    const float* __restrict__ i0, const float* __restrict__ i1,
    const float* __restrict__ i2, const float* __restrict__ i3,
    float* __restrict__ pooled)
{
    int bid = blockIdx.x;
    int m   = bid & 3;
    int bc  = bid >> 2;
    const float* src = (m == 0 ? i0 : m == 1 ? i1 : m == 2 ? i2 : i3)
                       + (size_t)bc * DWH;
    int t = threadIdx.x;
    int d   = t >> 3;
    int sub = t & 7;

    const float4* row = (const float4*)(src + (size_t)d * WH);
    float4 a0 = {0.f, 0.f, 0.f, 0.f}, a1 = {0.f, 0.f, 0.f, 0.f};
    #pragma unroll
    for (int j = 0; j < 16; ++j) {
        float4 u = row[sub + 8 * (2 * j)];
        float4 w = row[sub + 8 * (2 * j + 1)];
        a0.x += u.x; a0.y += u.y; a0.z += u.z; a0.w += u.w;
        a1.x += w.x; a1.y += w.y; a1.z += w.z; a1.w += w.w;
    }
    float s = (a0.x + a0.y) + (a0.z + a0.w) + (a1.x + a1.y) + (a1.z + a1.w);
    s += __shfl_down(s, 4, 64);
    s += __shfl_down(s, 2, 64);
    s += __shfl_down(s, 1, 64);
    if (sub == 0) pooled[bc * 128 + m * 32 + d] = s * (1.0f / 1024.0f);
}

// ---------------------------------------------------------------------------
// Kernel 2: attention weights + effective GEMM A-matrix + effective bias.
// ---------------------------------------------------------------------------
__global__ __launch_bounds__(64) void attn_kernel(
    const float* __restrict__ pooled,
    const float* __restrict__ Wq, const float* __restrict__ bq,
    const float* __restrict__ Wk, const float* __restrict__ bk,
    const float* __restrict__ Wc, const float* __restrict__ bcv,
    unsigned short* __restrict__ Amat, float* __restrict__ beff)
{
    int bc_idx = blockIdx.x;             // b*NC + c
    int lane = threadIdx.x;
    int e = lane & 31;
    const float* P = pooled + bc_idx * 128;

    float q = 0.f, kv[4] = {0.f, 0.f, 0.f, 0.f};
    for (int d = 0; d < 32; ++d) {
        float pq = P[d];
        float wq = Wq[e * 32 + d], wk = Wk[e * 32 + d];
        q += pq * wq;
        #pragma unroll
        for (int m = 0; m < 4; ++m) kv[m] += P[m * 32 + d] * wk;
    }
    q += bq[e];
    #pragma unroll
    for (int m = 0; m < 4; ++m) kv[m] += bk[e];

    float lg[4];
    #pragma unroll
    for (int m = 0; m < 4; ++m) {
        float p = q * kv[m];
        #pragma unroll
        for (int off = 16; off; off >>= 1) p += __shfl_xor(p, off, 32);
        lg[m] = p * 0.17677669529663687f;    // 1/sqrt(32)
    }
    float mx = fmaxf(fmaxf(lg[0], lg[1]), fmaxf(lg[2], lg[3]));
    float ex[4], s = 0.f;
    #pragma unroll
    for (int m = 0; m < 4; ++m) { ex[m] = __expf(lg[m] - mx); s += ex[m]; }
    float a[4];
    #pragma unroll
    for (int m = 0; m < 4; ++m) a[m] = ex[m] / s;

    int c = bc_idx & 255;
    if (lane == 0) {
        float be = 0.f;
        #pragma unroll
        for (int m = 0; m < 4; ++m) be += a[m] * bcv[m * NC + c];
        beff[bc_idx] = be;
    }
    unsigned short* Arow = Amat + (size_t)bc_idx * KTOT;
    #pragma unroll
    for (int j = 0; j < 16; ++j) {
        int k = j * 64 + lane;
        int m = k >> 8, cin = k & 255;
        float v = a[m] * Wc[(m * NC + c) * NC + cin];
        Arow[k] = f32_to_bf16(v);
    }
}

#define BM 128
#define BN 128
#define BK 64

static __device__ __forceinline__ int swzA(int row, int chunk) {
    // ushort units: row stride 64 ushorts (=128B), chunk = 8 ushorts (=16B)
    return row * 64 + ((chunk ^ (row & 7)) << 3);
}
static __device__ __forceinline__ int swzB(int row, int chunk) {
    return row * 64 + ((chunk ^ ((row >> 1) & 7)) << 3);
}

// ===========================================================================
// K3: all-bf16 GEMM (structure verified R13-R16, ~100 us). A and B staged
// via global_load_lds (pre-swizzled per-lane source, linear LDS dest),
// double-buffered one K-tile ahead; only in-loop wait is counted vmcnt(8).
// R17: B source addressing updated for the Bt2 layout (LDS contents and
// compute are byte-identical).
// ===========================================================================
__global__ __launch_bounds__(256, 2) void gemm2_kernel(
    const unsigned short* __restrict__ Amat,
    const unsigned short* __restrict__ Bt,
    const float* __restrict__ beff,
    float* __restrict__ out)
{
    __shared__ __align__(16) short As[2 * BM * BK];   // 32KB dbuf
    __shared__ __align__(16) short Bs[2 * BN * BK];   // 32KB dbuf

    int raw = blockIdx.x;
    int sb  = (raw & 7) * 256 + (raw >> 3);
    int ot = sb & 1;
    int xt = (sb >> 1) & 255;
    int b  = sb >> 9;
    int o0 = ot * BM, x0 = xt * BN;

    int t = threadIdx.x;
    int wave = t >> 6, lane = t & 63;
    int wr = wave >> 1, wc = wave & 1;
    int lrow = lane & 15, lk = lane >> 4;
    int lr8 = lane >> 3;
    int aq  = (lane & 7) ^ lr8;

    const unsigned short* asrc = Amat + ((size_t)b * NC + o0) * KTOT
                                 + (size_t)(wave * 32 + lr8) * KTOT + aq * 8;
    // Bt2[b][kt][kc=aq][X = xt*128 + xloc]: per-lane base; per-tile stride
    // 2,097,152 ushorts (4MB); per-instr(p) stride 64 ushorts (8 x-rows).
    const unsigned short* bsrc = Bt + (size_t)b * 16 * 2097152
                                 + (size_t)aq * 262144
                                 + ((size_t)xt * 128 + wave * 32 + lr8) * 8;

    f32x4 acc[4][4];
    #pragma unroll
    for (int mi = 0; mi < 4; ++mi)
        #pragma unroll
        for (int ni = 0; ni < 4; ++ni)
            acc[mi][ni] = (f32x4){0.f, 0.f, 0.f, 0.f};

    // ---- prologue: issue tile 0 into buf0 (8 vmem per wave) ----
    #pragma unroll
    for (int p = 0; p < 4; ++p)
        __builtin_amdgcn_global_load_lds(
            (const __attribute__((address_space(1))) unsigned int*)
                (asrc + (size_t)p * 8 * KTOT),
            (__attribute__((address_space(3))) unsigned int*)
                (As + (wave * 32 + p * 8) * 64), 16, 0, 0);
    #pragma unroll
    for (int p = 0; p < 4; ++p)
        __builtin_amdgcn_global_load_lds(
            (const __attribute__((address_space(1))) unsigned int*)
                (bsrc + (size_t)p * 64),
            (__attribute__((address_space(3))) unsigned int*)
                (Bs + (wave * 32 + p * 8) * 64), 16, 0, 0);
    __builtin_amdgcn_sched_barrier(0);

    #pragma unroll 1
    for (int it = 0; it < 16; ++it) {
        // ---- issue next tile -> buf^1 (8 vmem; last iter re-issues 15) ----
        int ja = (it < 15) ? it + 1 : 15;
        int bo = ((it + 1) & 1) * (BM * BK);
        #pragma unroll
        for (int p = 0; p < 4; ++p)
            __builtin_amdgcn_global_load_lds(
                (const __attribute__((address_space(1))) unsigned int*)
                    (asrc + (size_t)p * 8 * KTOT + ja * BK),
                (__attribute__((address_space(3))) unsigned int*)
                    (As + bo + (wave * 32 + p * 8) * 64), 16, 0, 0);
        #pragma unroll
        for (int p = 0; p < 4; ++p)
            __builtin_amdgcn_global_load_lds(
                (const __attribute__((address_space(1))) unsigned int*)
                    (bsrc + (size_t)ja * 2097152 + p * 64),
                (__attribute__((address_space(3))) unsigned int*)
                    (Bs + bo + (wave * 32 + p * 8) * 64), 16, 0, 0);
        __builtin_amdgcn_sched_barrier(0);

        // ---- current tile's 8 loads landed (8 newer in flight) ----
        asm volatile("s_waitcnt vmcnt(8)" ::: "memory");
        __builtin_amdgcn_s_barrier();
        __builtin_amdgcn_sched_barrier(0);

        // ---- compute on buf cur ----
        const short* Acur = As + (it & 1) * (BM * BK);
        const short* Bcur = Bs + (it & 1) * (BM * BK);
        #pragma unroll
        for (int kk = 0; kk < 2; ++kk) {
            int q = kk * 4 + lk;
            short8 af[4], bf[4];
            #pragma unroll
            for (int mi = 0; mi < 4; ++mi)
                af[mi] = *(const short8*)(&Acur[swzA(wr * 64 + mi * 16 + lrow, q)]);
            #pragma unroll
            for (int ni = 0; ni < 4; ++ni)
                bf[ni] = *(const short8*)(&Bcur[swzA(wc * 64 + ni * 16 + lrow, q)]);
            __builtin_amdgcn_s_setprio(1);
            #pragma unroll
            for (int mi = 0; mi < 4; ++mi)
                #pragma unroll
                for (int ni = 0; ni < 4; ++ni)
                    acc[mi][ni] = __builtin_amdgcn_mfma_f32_16x16x32_bf16(
                        af[mi], bf[ni], acc[mi][ni], 0, 0, 0);
            __builtin_amdgcn_s_setprio(0);
        }
        // ---- all waves done reading buf cur (next iter overwrites it) ----
        __builtin_amdgcn_s_barrier();
        __builtin_amdgcn_sched_barrier(0);
    }

    // ---- epilogue ----
    const float* beff_b = beff + b * NC + o0;
    float* outb = out + ((size_t)b * NC + o0) * DWH + x0;
    #pragma unroll
    for (int mi = 0; mi < 4; ++mi) {
        #pragma unroll
        for (int r4 = 0; r4 < 4; ++r4) {
            int row = wr * 64 + mi * 16 + lk * 4 + r4;
            float bias = beff_b[row];
            float* orow = outb + (size_t)row * DWH;
            #pragma unroll
            for (int ni = 0; ni < 4; ++ni) {
                int col = wc * 64 + ni * 16 + lrow;
                orow[col] = acc[mi][ni][r4] + bias;
            }
        }
    }
}

// ===========================================================================
// FALLBACK K3: R12 gemm (fp32 B reg-staged + cvt_pk).
// ===========================================================================
__global__ __launch_bounds__(256, 3) void gemm_kernel(
    const float* __restrict__ i0, const float* __restrict__ i1,
    const float* __restrict__ i2, const float* __restrict__ i3,
    const unsigned short* __restrict__ Amat,
    const float* __restrict__ beff,
    float* __restrict__ out)
{
    __shared__ __align__(16) short As[2 * BM * BK];
    __shared__ __align__(16) short Bs[BN * BK];

    int raw = blockIdx.x;
    int sb  = (raw & 7) * 256 + (raw >> 3);
    int ot = sb & 1;
    int xt = (sb >> 1) & 255;
    int b  = sb >> 9;
    int o0 = ot * BM, x0 = xt * BN;

    const unsigned short* Ab = Amat + ((size_t)b * NC + o0) * KTOT;

    int t = threadIdx.x;
    int wave = t >> 6, lane = t & 63;
    int wr = wave >> 1, wc = wave & 1;
    int lrow = lane & 15, lk = lane >> 4;

    f32x4 acc[4][4];
    #pragma unroll
    for (int mi = 0; mi < 4; ++mi)
        #pragma unroll
        for (int ni = 0; ni < 4; ++ni)
            acc[mi][ni] = (f32x4){0.f, 0.f, 0.f, 0.f};

    int xq = t & 31;
    int kb = (t >> 5) * 8;

    int ar = wave * 32 + (lane >> 3);
    int aq = (lane & 7) ^ (lane >> 3);
    const unsigned short* asrc = Ab + (size_t)ar * KTOT + aq * 8;

    float4 v[8];

    {
        #pragma unroll
        for (int p = 0; p < 4; ++p)
            __builtin_amdgcn_global_load_lds(
                (const __attribute__((address_space(1))) unsigned int*)
                    (asrc + (size_t)p * 8 * KTOT),
                (__attribute__((address_space(3))) unsigned int*)
                    (As + (wave * 32 + p * 8) * 64), 16, 0, 0);
        const float* Bb = i0 + (size_t)b * NC * DWH + x0;
        #pragma unroll
        for (int j = 0; j < 8; ++j)
            v[j] = *(const float4*)(Bb + (size_t)(kb + j) * DWH + xq * 4);
    }

    #pragma unroll 1
    for (int it = 0; it < KTOT / BK; ++it) {
        const short* Acur = As + (it & 1) * (BM * BK);
        short* Anx = As + ((it + 1) & 1) * (BM * BK);

        __builtin_amdgcn_s_barrier();
        __builtin_amdgcn_sched_barrier(0);

        {
            int ja = (it + 1 < 16) ? it + 1 : 15;
            #pragma unroll
            for (int p = 0; p < 4; ++p)
                __builtin_amdgcn_global_load_lds(
                    (const __attribute__((address_space(1))) unsigned int*)
                        (asrc + (size_t)p * 8 * KTOT + ja * BK),
                    (__attribute__((address_space(3))) unsigned int*)
                        (Anx + (wave * 32 + p * 8) * 64), 16, 0, 0);
        }
        __builtin_amdgcn_sched_barrier(0);

        uint4 pk[4];
        #pragma unroll
        for (int i = 0; i < 4; ++i) {
            unsigned w[4];
            #pragma unroll
            for (int j = 0; j < 4; ++j)
                w[j] = pack_bf16x2(((const float*)&v[2 * j])[i],
                                   ((const float*)&v[2 * j + 1])[i]);
            pk[i] = (uint4){w[0], w[1], w[2], w[3]};
        }

        {
            int itn = (it < 15) ? it + 1 : 15;
            int m = itn >> 2, cbase = (itn & 3) * 64;
            const float* Bb = (m == 0 ? i0 : m == 1 ? i1 : m == 2 ? i2 : i3)
                              + ((size_t)b * NC + cbase) * DWH + x0;
            #pragma unroll
            for (int j = 0; j < 8; ++j)
                v[j] = *(const float4*)(Bb + (size_t)(kb + j) * DWH + xq * 4);
        }
        __builtin_amdgcn_sched_barrier(0);

        #pragma unroll
        for (int i = 0; i < 4; ++i)
            *(uint4*)(&Bs[swzB(xq * 4 + i, t >> 5)]) = pk[i];

        asm volatile("s_waitcnt vmcnt(12) lgkmcnt(0)" ::: "memory");
        __builtin_amdgcn_s_barrier();
        __builtin_amdgcn_sched_barrier(0);

        #pragma unroll
        for (int kk = 0; kk < 2; ++kk) {
            int q = kk * 4 + lk;
            short8 af[4], bf[4];
            #pragma unroll
            for (int mi = 0; mi < 4; ++mi)
                af[mi] = *(const short8*)(&Acur[swzA(wr * 64 + mi * 16 + lrow, q)]);
            #pragma unroll
            for (int ni = 0; ni < 4; ++ni)
                bf[ni] = *(const short8*)(&Bs[swzB(wc * 64 + ni * 16 + lrow, q)]);
            __builtin_amdgcn_s_setprio(1);
            #pragma unroll
            for (int mi = 0; mi < 4; ++mi)
                #pragma unroll
                for (int ni = 0; ni < 4; ++ni)
                    acc[mi][ni] = __builtin_amdgcn_mfma_f32_16x16x32_bf16(
                        af[mi], bf[ni], acc[mi][ni], 0, 0, 0);
            __builtin_amdgcn_s_setprio(0);
        }
    }

    const float* beff_b = beff + b * NC + o0;
    float* outb = out + ((size_t)b * NC + o0) * DWH + x0;
    #pragma unroll
    for (int mi = 0; mi < 4; ++mi) {
        #pragma unroll
        for (int r4 = 0; r4 < 4; ++r4) {
            int row = wr * 64 + mi * 16 + lk * 4 + r4;
            float bias = beff_b[row];
            float* orow = outb + (size_t)row * DWH;
            #pragma unroll
            for (int ni = 0; ni < 4; ++ni) {
                int col = wc * 64 + ni * 16 + lrow;
                orow[col] = acc[mi][ni][r4] + bias;
            }
        }
    }
}

// ---------------------------------------------------------------------------
extern "C" void kernel_launch(void* const* d_in, const int* in_sizes, int n_in,
                              void* d_out, int out_size, void* d_ws, size_t ws_size,
                              hipStream_t stream) {
    const float* m1 = (const float*)d_in[0];
    const float* m2 = (const float*)d_in[1];
    const float* m3 = (const float*)d_in[2];
    const float* m4 = (const float*)d_in[3];
    const float* Wq = (const float*)d_in[4];
    const float* bq = (const float*)d_in[5];
    const float* Wk = (const float*)d_in[6];
    const float* bk = (const float*)d_in[7];
    const float* Wc = (const float*)d_in[8];
    const float* bcv = (const float*)d_in[9];
    float* out = (float*)d_out;

    const size_t BT_BYTES = (size_t)NB * KTOT * DWH * 2;   // 256 MB
    const size_t NEED = BT_BYTES + 524288 + 2097152 + 4096;

    if (ws_size >= NEED) {
        // transcode+pool -> attn -> all-bf16 gemm
        unsigned short* Btr   = (unsigned short*)d_ws;
        float* pooled         = (float*)((char*)d_ws + BT_BYTES);
        unsigned short* Amat  = (unsigned short*)((char*)d_ws + BT_BYTES + 524288);
        float* beff           = (float*)((char*)d_ws + BT_BYTES + 524288 + 2097152);

        transpool_kernel<<<16384, 256, 0, stream>>>(m1, m2, m3, m4, Btr, pooled);
        attn_kernel<<<NB * NC, 64, 0, stream>>>(pooled, Wq, bq, Wk, bk, Wc, bcv,
                                                Amat, beff);
        gemm2_kernel<<<2048, 256, 0, stream>>>(Amat, Btr, beff, out);
    } else {
        // FALLBACK: measured R12 path
        float* pooled        = (float*)d_ws;
        unsigned short* Amat = (unsigned short*)((char*)d_ws + 524288);
        float* beff          = (float*)((char*)d_ws + 524288 + 2097152);

        pool_kernel<<<NB * NC * 4, 256, 0, stream>>>(m1, m2, m3, m4, pooled);
        attn_kernel<<<NB * NC, 64, 0, stream>>>(pooled, Wq, bq, Wk, bk, Wc, bcv,
                                                Amat, beff);
        gemm_kernel<<<(NB) * (NC / BM) * (DWH / BN), 256, 0, stream>>>(
            m1, m2, m3, m4, Amat, beff, out);
    }
}